// Round 6
// baseline (574.405 us; speedup 1.0000x reference)
//
#include <hip/hip_runtime.h>
#include <stdint.h>

// Problem constants
#define NB 4096
#define NT 512
#define OT 513
#define TOTE (NB*OT)          // 2101248 elements per output matrix
#define LOSSOFF (2*TOTE)      // diff_loss slot

typedef float  f32x4 __attribute__((ext_vector_type(4)));
typedef __fp16 f16x8 __attribute__((ext_vector_type(8)));
typedef __fp16 f16x2 __attribute__((ext_vector_type(2)));

#define MFMA(A,B,C) __builtin_amdgcn_mfma_f32_16x16x32_f16((A),(B),(C),0,0,0)

// Barrier that drains LDS only (no vmcnt(0) drain -> global stores stay in flight)
__device__ __forceinline__ void wg_barrier() {
  asm volatile("s_waitcnt lgkmcnt(0)\n\ts_barrier" ::: "memory");
}

__device__ __forceinline__ float fast_tanh(float x) {
  float e = __builtin_amdgcn_exp2f(x * 2.8853900817779268f); // 2*log2(e)
  return __builtin_fmaf(-2.0f, __builtin_amdgcn_rcpf(1.0f + e), 1.0f);
}
// Vector tanh: per-component ops/order bit-identical to fast_tanh, but the
// mul/add/fma parts are expressed as f32x4 so the compiler emits v_pk_* ops.
__device__ __forceinline__ f32x4 tanh4(f32x4 x) {
  f32x4 m = x * 2.8853900817779268f;
  f32x4 e;
  e.x = __builtin_amdgcn_exp2f(m.x); e.y = __builtin_amdgcn_exp2f(m.y);
  e.z = __builtin_amdgcn_exp2f(m.z); e.w = __builtin_amdgcn_exp2f(m.w);
  f32x4 o = e + 1.0f;          // same add as 1.0f + e
  f32x4 r;
  r.x = __builtin_amdgcn_rcpf(o.x); r.y = __builtin_amdgcn_rcpf(o.y);
  r.z = __builtin_amdgcn_rcpf(o.z); r.w = __builtin_amdgcn_rcpf(o.w);
  return __builtin_elementwise_fma((f32x4)(-2.0f), r, (f32x4)(1.0f));
}
__device__ __forceinline__ float fast_silu(float x) {
  float e = __builtin_amdgcn_exp2f(x * -1.4426950408889634f); // -log2(e)
  return x * __builtin_amdgcn_rcpf(1.0f + e);
}
__device__ __forceinline__ uint32_t pk2(float a, float b) {
  union { f16x2 h; uint32_t u; } c;
  c.h = __builtin_amdgcn_cvt_pkrtz(a, b);
  return c.u;
}
__device__ __forceinline__ f16x8 pack8(f32x4 a, f32x4 b) {
  union { f16x8 v; f16x2 h[4]; } u;
  u.h[0] = __builtin_amdgcn_cvt_pkrtz(a.x, a.y);
  u.h[1] = __builtin_amdgcn_cvt_pkrtz(a.z, a.w);
  u.h[2] = __builtin_amdgcn_cvt_pkrtz(b.x, b.y);
  u.h[3] = __builtin_amdgcn_cvt_pkrtz(b.z, b.w);
  return u.v;
}

// ws layout (bytes):
//   [0, 1M)          wsz  : z_aug f32 [4096][64]
//   [1M, +228K)      wpak : packed A-frags (228 frags x 1 KB)
//   [1M+256K, +72K)  Ubuf : U_ext = W3@[W1|decW|0], f32 [128][144]
//   [1M+384K, 576B)  cbuf : c_ext = [b3@W1 (128) | b3@decW (2) | 0 (14)]
#define WS_WPAK (1u<<20)
#define WS_UBUF ((1u<<20) + (256u<<10))
#define WS_CBUF ((1u<<20) + (384u<<10))

// ---------------------------------------------------------------------------
// Kernel 0: compose U_ext (128x144) and c_ext (144); zero the loss slot.
// ---------------------------------------------------------------------------
__global__ void compose_kernel(const float* __restrict__ oW1, const float* __restrict__ oW3,
                               const float* __restrict__ ob3, const float* __restrict__ dW,
                               float* __restrict__ Ubuf, float* __restrict__ cbuf,
                               float* __restrict__ dout) {
  int g = blockIdx.x, tid = threadIdx.x;
  if (g < 72) {
    int e = g * 256 + tid;          // 0..18431
    int i = e / 144, j = e - i * 144;
    float s = 0.f;
    if (j < 128) {
      #pragma unroll 4
      for (int k = 0; k < 64; k++) s = __builtin_fmaf(oW3[i * 64 + k], oW1[k * 128 + j], s);
    } else if (j < 130) {
      int cc = j - 128;
      for (int k = 0; k < 64; k++) s = __builtin_fmaf(oW3[i * 64 + k], dW[k * 2 + cc], s);
    }
    Ubuf[i * 144 + j] = s;
  } else {
    if (tid < 144) {
      float s = 0.f;
      if (tid < 128) {
        for (int k = 0; k < 64; k++) s = __builtin_fmaf(ob3[k], oW1[k * 128 + tid], s);
      } else if (tid < 130) {
        int cc = tid - 128;
        for (int k = 0; k < 64; k++) s = __builtin_fmaf(ob3[k], dW[k * 2 + cc], s);
      }
      cbuf[tid] = s;
    }
    if (tid == 255) dout[LOSSOFF] = 0.0f;
  }
}

// ---------------------------------------------------------------------------
// Kernel 1: repack weights ([K][M] row-major f32) into MFMA A-operand f16
// fragments: A[m=lane&15][k=kt*32+(lane>>4)*8+j].  1 KB per frag.
//   [0,16)  ode_W1 (M=128,Kt=2)   [16,48)  ode_W2 (M=128,Kt=4)
//   [48,50) decW^T (M=16[2 real],Kt=2)     [50,64)  unused
//   [64,80) den_W1 (M=128,Kt=2)   [80,96)  den_W2 (M=64,Kt=4)
//   [96,192) proj_W (M=64,Kt=24)  [192,228) U_ext (M=144,Kt=4)
// ---------------------------------------------------------------------------
__global__ void pack_kernel(const float* __restrict__ oW1, const float* __restrict__ oW2,
                            const float* __restrict__ dW,  const float* __restrict__ dW1,
                            const float* __restrict__ dW2, const float* __restrict__ pW,
                            const float* __restrict__ Ubuf, char* __restrict__ wdst) {
  int g = blockIdx.x * 256 + threadIdx.x;
  int fid = g >> 6, lane = g & 63;
  if (fid >= 228 || (fid >= 50 && fid < 64)) return;
  int m4 = lane & 15;
  if (fid >= 48 && fid < 50) {       // decW^T: A[m][k] = decW[k][m], m<2
    int kt = fid - 48;
    int k0 = kt * 32 + (lane >> 4) * 8;
    f16x8 out;
    #pragma unroll
    for (int j = 0; j < 8; j++) out[j] = (m4 < 2) ? (__fp16)dW[(k0 + j) * 2 + m4] : (__fp16)0.f;
    *(f16x8*)(wdst + (size_t)(fid * 64 + lane) * 16) = out;
    return;
  }
  const float* src; int Kt, M, base;
  if      (fid < 16)  { src = oW1;  Kt = 2;  M = 128; base = 0;   }
  else if (fid < 48)  { src = oW2;  Kt = 4;  M = 128; base = 16;  }
  else if (fid < 80)  { src = dW1;  Kt = 2;  M = 128; base = 64;  }
  else if (fid < 96)  { src = dW2;  Kt = 4;  M = 64;  base = 80;  }
  else if (fid < 192) { src = pW;   Kt = 24; M = 64;  base = 96;  }
  else                { src = Ubuf; Kt = 4;  M = 144; base = 192; }
  int local = fid - base;
  int mt = local / Kt, kt = local % Kt;
  int m  = mt * 16 + m4;
  int k0 = kt * 32 + (lane >> 4) * 8;
  f16x8 out;
  #pragma unroll
  for (int j = 0; j < 8; j++) out[j] = (__fp16)src[(size_t)(k0 + j) * M + m];
  *(f16x8*)(wdst + (size_t)(fid * 64 + lane) * 16) = out;
}

// ---------------------------------------------------------------------------
// Kernel 2: prologue (unchanged — verified).  256 WGs x 512 threads.
// ---------------------------------------------------------------------------
__global__ __launch_bounds__(512, 2) void prologue_kernel(
    const float* __restrict__ bert, const float* __restrict__ eps,
    const float* __restrict__ projb, const float* __restrict__ lng,
    const float* __restrict__ lnb,  const float* __restrict__ lns,
    const float* __restrict__ db1,  const float* __restrict__ db2,
    const char* __restrict__ wpack, float* __restrict__ wsz,
    float* __restrict__ dout) {
  __shared__ __attribute__((aligned(16))) char sZ[16 * 128];
  __shared__ __attribute__((aligned(16))) char sH[16 * 256];
  __shared__ f32x4  sScr[4 * 64];
  __shared__ float2 sMV[64];
  __shared__ float  sLsum[4];

  const int tid  = threadIdx.x;
  const int wave = tid >> 6, lane = tid & 63;
  const int q = lane >> 4, b = lane & 15;
  const int bg = blockIdx.x * 16 + b;
  const int b7 = b & 7;
  const f16x8* wp = (const f16x8*)wpack;
  const int u0 = wave * 16 + q * 4;

  const int zr0 = b * 128 + ((q    ) ^ b7) * 16;
  const int zr1 = b * 128 + ((q + 4) ^ b7) * 16;
  int hr[4];
  #pragma unroll
  for (int s = 0; s < 4; s++) hr[s] = b * 256 + ((4 * s + q) ^ b7) * 16;
  const int hw = b * 256 + (((2 * wave + (q >> 1)) ^ b7) * 16) + (q & 1) * 8;
  const int zw = b * 128 + (((2 * (wave & 3) + (q >> 1)) ^ b7) * 16) + (q & 1) * 8;

  const int mt = wave & 3, kh = wave >> 2;
  f32x4 hA = {0,0,0,0}, hB = {0,0,0,0};
  #pragma unroll 4
  for (int i = 0; i < 12; i++) {
    int kt = kh * 12 + i;
    f16x8 af = wp[(size_t)(96 + mt * 24 + kt) * 64 + lane];
    const float* bp = bert + (size_t)bg * 768 + kt * 32 + q * 8;
    f32x4 f0 = *(const f32x4*)bp;
    f32x4 f1 = *(const f32x4*)(bp + 4);
    f16x8 bf = pack8(f0, f1);
    if (i & 1) hB = MFMA(af, bf, hB); else hA = MFMA(af, bf, hA);
  }
  f32x4 hacc = hA + hB;
  if (wave >= 4) sScr[(wave - 4) * 64 + lane] = hacc;
  __syncthreads();

  f32x4 h = {0,0,0,0}, zc = {0,0,0,0};
  if (wave < 4) {
    h = hacc + sScr[wave * 64 + lane];
    h.x += projb[u0 + 0]; h.y += projb[u0 + 1];
    h.z += projb[u0 + 2]; h.w += projb[u0 + 3];
    float s1 = h.x + h.y + h.z + h.w;
    float s2 = h.x*h.x + h.y*h.y + h.z*h.z + h.w*h.w;
    s1 += __shfl_xor(s1, 16); s1 += __shfl_xor(s1, 32);
    s2 += __shfl_xor(s2, 16); s2 += __shfl_xor(s2, 32);
    if (q == 0) sMV[wave * 16 + b] = make_float2(s1, s2);
  }
  __syncthreads();
  if (wave < 4) {
    float t1 = 0.f, t2 = 0.f;
    #pragma unroll
    for (int w2 = 0; w2 < 4; w2++) { float2 m = sMV[w2 * 16 + b]; t1 += m.x; t2 += m.y; }
    float mu  = t1 * (1.0f / 64.0f);
    float var = t2 * (1.0f / 64.0f) - mu * mu;
    float rs  = rsqrtf(var + 1e-5f);
    float sigma = logf(1.0f + expf(lns[0]));
    f32x4 e = *(const f32x4*)(eps + (size_t)bg * 64 + u0);
    zc.x = __builtin_fmaf((h.x - mu) * rs, lng[u0+0], lnb[u0+0]);
    zc.y = __builtin_fmaf((h.y - mu) * rs, lng[u0+1], lnb[u0+1]);
    zc.z = __builtin_fmaf((h.z - mu) * rs, lng[u0+2], lnb[u0+2]);
    zc.w = __builtin_fmaf((h.w - mu) * rs, lng[u0+3], lnb[u0+3]);
    f32x4 zn = zc + sigma * e;
    *(uint2*)(sZ + zw) = make_uint2(pk2(zn.x, zn.y), pk2(zn.z, zn.w));
  }
  __syncthreads();
  {
    f16x8 w0 = wp[(size_t)(64 + wave * 2 + 0) * 64 + lane];
    f16x8 w1 = wp[(size_t)(64 + wave * 2 + 1) * 64 + lane];
    f16x8 bz0 = *(const f16x8*)(sZ + zr0);
    f16x8 bz1 = *(const f16x8*)(sZ + zr1);
    f32x4 bias = { db1[u0+0], db1[u0+1], db1[u0+2], db1[u0+3] };
    f32x4 acc = MFMA(w0, bz0, bias);
    acc = MFMA(w1, bz1, acc);
    *(uint2*)(sH + hw) = make_uint2(pk2(fast_silu(acc.x), fast_silu(acc.y)),
                                    pk2(fast_silu(acc.z), fast_silu(acc.w)));
  }
  __syncthreads();
  if (wave < 4) {
    f16x8 w0 = wp[(size_t)(80 + wave * 4 + 0) * 64 + lane];
    f16x8 w1 = wp[(size_t)(80 + wave * 4 + 1) * 64 + lane];
    f16x8 w2 = wp[(size_t)(80 + wave * 4 + 2) * 64 + lane];
    f16x8 w3 = wp[(size_t)(80 + wave * 4 + 3) * 64 + lane];
    f16x8 g0 = *(const f16x8*)(sH + hr[0]);
    f16x8 g1 = *(const f16x8*)(sH + hr[1]);
    f16x8 g2 = *(const f16x8*)(sH + hr[2]);
    f16x8 g3 = *(const f16x8*)(sH + hr[3]);
    f32x4 bias = { db2[u0+0], db2[u0+1], db2[u0+2], db2[u0+3] };
    const f32x4 z4 = {0,0,0,0};
    f32x4 aA = MFMA(w0, g0, bias); aA = MFMA(w1, g1, aA);
    f32x4 aB = MFMA(w2, g2, z4);   aB = MFMA(w3, g3, aB);
    f32x4 za = aA + aB;
    *(f32x4*)(wsz + (size_t)bg * 64 + u0) = za;
    f32x4 d = za - zc;
    float sl = d.x*d.x + d.y*d.y + d.z*d.z + d.w*d.w;
    const int offs[6] = {1, 2, 4, 8, 16, 32};
    #pragma unroll
    for (int i = 0; i < 6; i++) sl += __shfl_xor(sl, offs[i]);
    if (lane == 0) sLsum[wave] = sl;
  }
  __syncthreads();
  if (tid == 0)
    atomicAdd(dout + LOSSOFF,
              (sLsum[0] + sLsum[1] + sLsum[2] + sLsum[3]) * (1.0f / 262144.0f));
}

// ---------------------------------------------------------------------------
// Kernel 3: ODE scan — 8-row "fat" WGs with REPLICATED h-tiles (R4 post-
// mortem fix).  512 WGs x 256 threads (4 waves), 8 REAL rows/WG, 2 WGs/CU
// (independent barrier domains).  R4's failure: lanes b/b+8 reading the SAME
// address compressed the chunk space to 8 bank-group positions -> 4 distinct
// addresses per bank group per ds_read_b128 (SQ_LDS_BANK_CONFLICT 8.4M->33.5M).
// Fix: h is stored TWICE (copy A at +0, copy B at +2048 with chunk positions
// rotated +4 bank groups).  Lanes b<8 read copy A, lanes b>=8 read copy B:
// 64 UNIQUE addresses/read covering 1KB with exactly 8 addresses per bank
// group — the same profile R3 measured as fine.  Hi lanes compute exact
// duplicates (discarded), so per-row numerics are bit-identical to R0/R3.
// Each wave owns 2 M-tiles (T=wave, wave+4); wave 3 owns decode tile 8 with
// the R3 deferred-decode X/Y scheme.  Real lanes write both copies.
// ---------------------------------------------------------------------------
__global__ __launch_bounds__(256, 2) void ode_kernel(
    const float* __restrict__ wsz, const char* __restrict__ wpack,
    const float* __restrict__ ob1, const float* __restrict__ cbuf,
    const float* __restrict__ ob2, const float* __restrict__ decb,
    float* __restrict__ dout) {
  __shared__ __attribute__((aligned(16))) char sH1[4096];  // h1 f16 [copy][8][128]
  __shared__ __attribute__((aligned(16))) char sH2[4096];  // h2 f16 [copy][8][128]

  const int tid  = threadIdx.x;
  const int wave = tid >> 6, lane = tid & 63;
  const int q = lane >> 4, b = lane & 15;
  const int br = b & 7;              // real row index (lanes b>=8 duplicate)
  const int rep = b >> 3;            // 0: copy A reader, 1: copy B reader
  const bool rw = (b < 8);           // real-write lane
  const f16x8* wp = (const f16x8*)wpack;
  const float dtc = 1.0f / 512.0f;
  const f32x4 dt4 = {dtc, dtc, dtc, dtc};
  const f32x4 zero4 = {0,0,0,0};

  // Read addrs: chunk c of row br sits at pos (c^br) in copy A and
  // ((c^br)+4)&15 in copy B.  Per instruction: 64 unique addresses, 8 per
  // bank group (R3-verified profile).
  int rd[4];
  #pragma unroll
  for (int kt = 0; kt < 4; kt++) {
    int c = kt * 4 + q;
    rd[kt] = rep * 2048 + br * 256 + ((((c) ^ br) + rep * 4) & 15) * 16;
  }
  // Write addrs (both copies, real lanes only).
  int wrA[2], wrB[2];
  #pragma unroll
  for (int s = 0; s < 2; s++) {
    int T = wave + 4 * s;
    int cw = T * 2 + (q >> 1);
    int p  = (cw ^ br) & 15;
    wrA[s] = br * 256 + p * 16 + (q & 1) * 8;
    wrB[s] = 2048 + br * 256 + (((p + 4) & 15)) * 16 + (q & 1) * 8;
  }

  // Persistent weight fragments: two owned tiles per wave (R1 mapping).
  f16x8 w2f[2][4], uf[2][4], uf8[4];
  #pragma unroll
  for (int s = 0; s < 2; s++) {
    int T = wave + 4 * s;
    #pragma unroll
    for (int kt = 0; kt < 4; kt++) {
      w2f[s][kt] = wp[(size_t)(16  + T * 4 + kt) * 64 + lane];
      uf [s][kt] = wp[(size_t)(192 + T * 4 + kt) * 64 + lane];
    }
  }
  const bool dec = (wave == 3);
  if (dec) {
    #pragma unroll
    for (int kt = 0; kt < 4; kt++)
      uf8[kt] = wp[(size_t)(192 + 32 + kt) * 64 + lane];          // U_ext tile 8
  }
  f32x4 b2f[2], cw[2];
  #pragma unroll
  for (int s = 0; s < 2; s++) {
    int T = wave + 4 * s;
    b2f[s] = *(const f32x4*)(ob2  + T * 16 + q * 4);
    cw [s] = *(const f32x4*)(cbuf + T * 16 + q * 4);
  }
  const f32x4 c8 = *(const f32x4*)(cbuf + 128 + q * 4);           // tile 8 const

  // ---- init: G = z@W1 + b1 ; Gd = z@decW + decb ; h1_0 -> sH1 ; store p0 ----
  const int bg = blockIdx.x * 8 + br;
  const float* zrow = wsz + (size_t)bg * 64;
  f32x4 z0a = *(const f32x4*)(zrow + q * 8);
  f32x4 z0b = *(const f32x4*)(zrow + q * 8 + 4);
  f32x4 z1a = *(const f32x4*)(zrow + 32 + q * 8);
  f32x4 z1b = *(const f32x4*)(zrow + 32 + q * 8 + 4);
  f16x8 zf0 = pack8(z0a, z0b);
  f16x8 zf1 = pack8(z1a, z1b);

  f32x4 G[2];
  #pragma unroll
  for (int s = 0; s < 2; s++) {
    int T = wave + 4 * s;
    f32x4 b1v = *(const f32x4*)(ob1 + T * 16 + q * 4);
    G[s] = MFMA(wp[(size_t)(T * 2 + 0) * 64 + lane], zf0, b1v);
    G[s] = MFMA(wp[(size_t)(T * 2 + 1) * 64 + lane], zf1, G[s]);
    f32x4 th = tanh4(G[s]);
    if (rw) {
      uint2 v = make_uint2(pk2(th.x, th.y), pk2(th.z, th.w));
      *(uint2*)(sH1 + wrA[s]) = v;
      *(uint2*)(sH1 + wrB[s]) = v;
    }
  }

  f32x4 Gd = zero4;
  float* const outp_p = dout + (size_t)bg * OT;
  float* const outp_s = dout + (size_t)TOTE + (size_t)bg * OT;
  if (dec) {
    f32x4 b1d = zero4;
    if (q == 0) { b1d.x = decb[0]; b1d.y = decb[1]; }
    Gd = MFMA(wp[(size_t)48 * 64 + lane], zf0, b1d);
    Gd = MFMA(wp[(size_t)49 * 64 + lane], zf1, Gd);
    if (q == 0 && rw) { outp_p[0] = Gd.x; outp_s[0] = Gd.y; }
  }
  wg_barrier();

  // ---- phase A: h2 = tanh(h1@W2 + b2) -> sH2 (both tiles, both copies) ----
  #define PHASE_A() do {                                                     \
    f16x8 p0 = *(const f16x8*)(sH1 + rd[0]);                                 \
    f16x8 p1 = *(const f16x8*)(sH1 + rd[1]);                                 \
    f16x8 p2 = *(const f16x8*)(sH1 + rd[2]);                                 \
    f16x8 p3 = *(const f16x8*)(sH1 + rd[3]);                                 \
    f32x4 A0 = MFMA(w2f[0][0], p0, b2f[0]);                                  \
    f32x4 A1 = MFMA(w2f[1][0], p0, b2f[1]);                                  \
    A0 = MFMA(w2f[0][1], p1, A0);                                            \
    A1 = MFMA(w2f[1][1], p1, A1);                                            \
    f32x4 B0 = MFMA(w2f[0][2], p2, zero4);                                   \
    f32x4 B1 = MFMA(w2f[1][2], p2, zero4);                                   \
    B0 = MFMA(w2f[0][3], p3, B0);                                            \
    B1 = MFMA(w2f[1][3], p3, B1);                                            \
    f32x4 t0 = tanh4(A0 + B0);                                               \
    f32x4 t1 = tanh4(A1 + B1);                                               \
    if (rw) {                                                                \
      uint2 v0 = make_uint2(pk2(t0.x, t0.y), pk2(t0.z, t0.w));               \
      uint2 v1 = make_uint2(pk2(t1.x, t1.y), pk2(t1.z, t1.w));               \
      *(uint2*)(sH2 + wrA[0]) = v0;                                          \
      *(uint2*)(sH2 + wrB[0]) = v0;                                          \
      *(uint2*)(sH2 + wrA[1]) = v1;                                          \
      *(uint2*)(sH2 + wrB[1]) = v1;                                          \
    }                                                                        \
  } while (0)

  // ---- phase B G-update from read-set (Ra..Rd), write h1' (both tiles) ----
  #define PHASE_B_UPD(Ra,Rb,Rc,Rd_) do {                                     \
    f32x4 D0 = MFMA(uf[0][0], Ra, cw[0]);                                    \
    f32x4 D1 = MFMA(uf[1][0], Ra, cw[1]);                                    \
    D0 = MFMA(uf[0][1], Rb, D0);                                             \
    D1 = MFMA(uf[1][1], Rb, D1);                                             \
    f32x4 E0 = MFMA(uf[0][2], Rc, zero4);                                    \
    f32x4 E1 = MFMA(uf[1][2], Rc, zero4);                                    \
    E0 = MFMA(uf[0][3], Rd_, E0);                                            \
    E1 = MFMA(uf[1][3], Rd_, E1);                                            \
    G[0] = __builtin_elementwise_fma(dt4, D0 + E0, G[0]);                    \
    G[1] = __builtin_elementwise_fma(dt4, D1 + E1, G[1]);                    \
    f32x4 t0 = tanh4(G[0]);                                                  \
    f32x4 t1 = tanh4(G[1]);                                                  \
    if (rw) {                                                                \
      uint2 v0 = make_uint2(pk2(t0.x, t0.y), pk2(t0.z, t0.w));               \
      uint2 v1 = make_uint2(pk2(t1.x, t1.y), pk2(t1.z, t1.w));               \
      *(uint2*)(sH1 + wrA[0]) = v0;                                          \
      *(uint2*)(sH1 + wrB[0]) = v0;                                          \
      *(uint2*)(sH1 + wrA[1]) = v1;                                          \
      *(uint2*)(sH1 + wrB[1]) = v1;                                          \
    }                                                                        \
  } while (0)

  // ---- deferred decoder update for the PREVIOUS step's h2 (regs only) ----
  #define DECODE(Ra,Rb,Rc,Rd_) do {                                         \
    f32x4 e  = MFMA(uf8[0], Ra, c8);                                         \
    e  = MFMA(uf8[1], Rb, e);                                                \
    f32x4 e2 = MFMA(uf8[2], Rc, zero4);                                      \
    e2 = MFMA(uf8[3], Rd_, e2);                                              \
    Gd.x = __builtin_fmaf(dtc, e.x + e2.x, Gd.x);                            \
    Gd.y = __builtin_fmaf(dtc, e.y + e2.y, Gd.y);                            \
  } while (0)

  f16x8 X0, X1, X2, X3, Y0, Y1, Y2, Y3;
  #pragma unroll 1
  for (int t = 0; t < NT; t += 2) {
    // ======== step t (even): reads -> X; decode step t-1 (Y) in read window
    PHASE_A();
    wg_barrier();
    X0 = *(const f16x8*)(sH2 + rd[0]);
    X1 = *(const f16x8*)(sH2 + rd[1]);
    X2 = *(const f16x8*)(sH2 + rd[2]);
    X3 = *(const f16x8*)(sH2 + rd[3]);
    if (dec && t > 0) {
      DECODE(Y0, Y1, Y2, Y3);
      if (q == 0 && rw) { outp_p[t] = Gd.x; outp_s[t] = Gd.y; }
    }
    PHASE_B_UPD(X0, X1, X2, X3);
    wg_barrier();

    // ======== step t+1 (odd): reads -> Y; decode step t (X) in read window
    PHASE_A();
    wg_barrier();
    Y0 = *(const f16x8*)(sH2 + rd[0]);
    Y1 = *(const f16x8*)(sH2 + rd[1]);
    Y2 = *(const f16x8*)(sH2 + rd[2]);
    Y3 = *(const f16x8*)(sH2 + rd[3]);
    if (dec) {
      DECODE(X0, X1, X2, X3);
      if (q == 0 && rw) { outp_p[t + 1] = Gd.x; outp_s[t + 1] = Gd.y; }
    }
    PHASE_B_UPD(Y0, Y1, Y2, Y3);
    wg_barrier();
  }
  // epilogue: decode for step NT-1 (held in Y)
  if (dec) {
    DECODE(Y0, Y1, Y2, Y3);
    if (q == 0 && rw) { outp_p[NT] = Gd.x; outp_s[NT] = Gd.y; }
  }
  #undef PHASE_A
  #undef PHASE_B_UPD
  #undef DECODE
}

// ---------------------------------------------------------------------------
extern "C" void kernel_launch(void* const* d_in, const int* in_sizes, int n_in,
                              void* d_out, int out_size, void* d_ws, size_t ws_size,
                              hipStream_t stream) {
  const float* bert  = (const float*)d_in[0];
  const float* eps   = (const float*)d_in[3];
  const float* projW = (const float*)d_in[4];
  const float* projb = (const float*)d_in[5];
  const float* lng   = (const float*)d_in[6];
  const float* lnb   = (const float*)d_in[7];
  const float* lns   = (const float*)d_in[8];
  const float* denW1 = (const float*)d_in[9];
  const float* denb1 = (const float*)d_in[10];
  const float* denW2 = (const float*)d_in[11];
  const float* denb2 = (const float*)d_in[12];
  const float* odeW1 = (const float*)d_in[13];
  const float* odeb1 = (const float*)d_in[14];
  const float* odeW2 = (const float*)d_in[15];
  const float* odeb2 = (const float*)d_in[16];
  const float* odeW3 = (const float*)d_in[17];
  // d_in[18] = odeb3 (folded into cbuf), d_in[19] = decW, d_in[20] = decb
  const float* odeb3 = (const float*)d_in[18];
  const float* decW  = (const float*)d_in[19];
  const float* decb  = (const float*)d_in[20];
  float* dout = (float*)d_out;

  float* wsz  = (float*)d_ws;
  char*  wpak = (char*)d_ws + WS_WPAK;
  float* Ubuf = (float*)((char*)d_ws + WS_UBUF);
  float* cbuf = (float*)((char*)d_ws + WS_CBUF);

  compose_kernel<<<73, 256, 0, stream>>>(odeW1, odeW3, odeb3, decW, Ubuf, cbuf, dout);
  pack_kernel<<<57, 256, 0, stream>>>(odeW1, odeW2, decW, denW1, denW2, projW, Ubuf, wpak);
  prologue_kernel<<<256, 512, 0, stream>>>(bert, eps, projb, lng, lnb, lns,
                                           denb1, denb2, wpak, wsz, dout);
  ode_kernel<<<512, 256, 0, stream>>>(wsz, wpak, odeb1, cbuf, odeb2, decb, dout);
}

// Round 7
// 400.903 us; speedup vs baseline: 1.4328x; 1.4328x over previous
//
#include <hip/hip_runtime.h>
#include <stdint.h>

// Problem constants
#define NB 4096
#define NT 512
#define OT 513
#define TOTE (NB*OT)          // 2101248 elements per output matrix
#define LOSSOFF (2*TOTE)      // diff_loss slot

typedef float  f32x4 __attribute__((ext_vector_type(4)));
typedef __fp16 f16x8 __attribute__((ext_vector_type(8)));
typedef __fp16 f16x2 __attribute__((ext_vector_type(2)));

#define MFMA(A,B,C) __builtin_amdgcn_mfma_f32_16x16x32_f16((A),(B),(C),0,0,0)

// Barrier that drains LDS only (no vmcnt(0) drain -> global stores stay in flight)
__device__ __forceinline__ void wg_barrier() {
  asm volatile("s_waitcnt lgkmcnt(0)\n\ts_barrier" ::: "memory");
}

// Vector tanh: per-component ops/order bit-identical to the verified scalar
// fast_tanh, but mul/add/fma expressed as f32x4 so the compiler emits v_pk_*.
__device__ __forceinline__ f32x4 tanh4(f32x4 x) {
  f32x4 m = x * 2.8853900817779268f;   // 2*log2(e)
  f32x4 e;
  e.x = __builtin_amdgcn_exp2f(m.x); e.y = __builtin_amdgcn_exp2f(m.y);
  e.z = __builtin_amdgcn_exp2f(m.z); e.w = __builtin_amdgcn_exp2f(m.w);
  f32x4 o = e + 1.0f;
  f32x4 r;
  r.x = __builtin_amdgcn_rcpf(o.x); r.y = __builtin_amdgcn_rcpf(o.y);
  r.z = __builtin_amdgcn_rcpf(o.z); r.w = __builtin_amdgcn_rcpf(o.w);
  return __builtin_elementwise_fma((f32x4)(-2.0f), r, (f32x4)(1.0f));
}
__device__ __forceinline__ float fast_silu(float x) {
  float e = __builtin_amdgcn_exp2f(x * -1.4426950408889634f); // -log2(e)
  return x * __builtin_amdgcn_rcpf(1.0f + e);
}
__device__ __forceinline__ uint32_t pk2(float a, float b) {
  union { f16x2 h; uint32_t u; } c;
  c.h = __builtin_amdgcn_cvt_pkrtz(a, b);
  return c.u;
}
__device__ __forceinline__ f16x8 pack8(f32x4 a, f32x4 b) {
  union { f16x8 v; f16x2 h[4]; } u;
  u.h[0] = __builtin_amdgcn_cvt_pkrtz(a.x, a.y);
  u.h[1] = __builtin_amdgcn_cvt_pkrtz(a.z, a.w);
  u.h[2] = __builtin_amdgcn_cvt_pkrtz(b.x, b.y);
  u.h[3] = __builtin_amdgcn_cvt_pkrtz(b.z, b.w);
  return u.v;
}

// ws layout (bytes):
//   [0, 1M)          wsz  : z_aug f32 [4096][64]
//   [1M, +228K)      wpak : packed A-frags (228 frags x 1 KB)
//   [1M+384K, 576B)  cbuf : c_ext = [b3@W1 (128) | b3@decW (2) | 0 (14)]
#define WS_WPAK (1u<<20)
#define WS_CBUF ((1u<<20) + (384u<<10))

// ---------------------------------------------------------------------------
// Kernel 1 (now also subsumes the old compose_kernel): repack weights
// ([K][M] row-major f32) into MFMA A-operand f16 fragments:
// A[m=lane&15][k=kt*32+(lane>>4)*8+j].  1 KB per frag.
//   [0,16)  ode_W1 (M=128,Kt=2)   [16,48)  ode_W2 (M=128,Kt=4)
//   [48,50) decW^T (M=16[2 real],Kt=2)     [50,64)  unused
//   [64,80) den_W1 (M=128,Kt=2)   [80,96)  den_W2 (M=64,Kt=4)
//   [96,192) proj_W (M=64,Kt=24)
//   [192,228) U_ext^T computed ON THE FLY: A[m][k] = U[k][m] =
//       sum_{k64} oW3[k*64+k64] * W1ext[k64][m]  (same serial fma order as
//       the old compose_kernel -> bit-identical U).
// Tail block (fid>=228, grid 58): cbuf (c_ext) + zero the loss slot.
// ---------------------------------------------------------------------------
__global__ void pack_kernel(const float* __restrict__ oW1, const float* __restrict__ oW2,
                            const float* __restrict__ dW,  const float* __restrict__ dW1,
                            const float* __restrict__ dW2, const float* __restrict__ pW,
                            const float* __restrict__ oW3, const float* __restrict__ ob3,
                            float* __restrict__ cbuf, char* __restrict__ wdst,
                            float* __restrict__ dout) {
  int g = blockIdx.x * 256 + threadIdx.x;
  int fid = g >> 6, lane = g & 63;
  if (fid >= 228) {                  // tail block: cbuf + loss zero
    int tid = g - 228 * 64;          // 0..255
    if (tid < 144) {
      float s = 0.f;
      if (tid < 128) {
        for (int k = 0; k < 64; k++) s = __builtin_fmaf(ob3[k], oW1[k * 128 + tid], s);
      } else if (tid < 130) {
        int cc = tid - 128;
        for (int k = 0; k < 64; k++) s = __builtin_fmaf(ob3[k], dW[k * 2 + cc], s);
      }
      cbuf[tid] = s;
    }
    if (tid == 255) dout[LOSSOFF] = 0.0f;
    return;
  }
  if (fid >= 50 && fid < 64) return;
  int m4 = lane & 15;
  if (fid >= 48 && fid < 50) {       // decW^T: A[m][k] = decW[k][m], m<2
    int kt = fid - 48;
    int k0 = kt * 32 + (lane >> 4) * 8;
    f16x8 out;
    #pragma unroll
    for (int j = 0; j < 8; j++) out[j] = (m4 < 2) ? (__fp16)dW[(k0 + j) * 2 + m4] : (__fp16)0.f;
    *(f16x8*)(wdst + (size_t)(fid * 64 + lane) * 16) = out;
    return;
  }
  if (fid >= 192) {                  // U_ext^T on the fly (old compose inline)
    int local = fid - 192, mt = local >> 2, kt = local & 3;
    int m  = mt * 16 + m4;           // U column, 0..143
    int k0 = kt * 32 + (lane >> 4) * 8;
    f16x8 out;
    #pragma unroll
    for (int j = 0; j < 8; j++) {
      float s = 0.f;
      const float* w3r = oW3 + (size_t)(k0 + j) * 64;
      if (m < 128) {
        for (int k = 0; k < 64; k++) s = __builtin_fmaf(w3r[k], oW1[k * 128 + m], s);
      } else if (m < 130) {
        int cc = m - 128;
        for (int k = 0; k < 64; k++) s = __builtin_fmaf(w3r[k], dW[k * 2 + cc], s);
      }
      out[j] = (__fp16)s;
    }
    *(f16x8*)(wdst + (size_t)(fid * 64 + lane) * 16) = out;
    return;
  }
  const float* src; int Kt, M, base;
  if      (fid < 16)  { src = oW1;  Kt = 2;  M = 128; base = 0;   }
  else if (fid < 48)  { src = oW2;  Kt = 4;  M = 128; base = 16;  }
  else if (fid < 80)  { src = dW1;  Kt = 2;  M = 128; base = 64;  }
  else if (fid < 96)  { src = dW2;  Kt = 4;  M = 64;  base = 80;  }
  else                { src = pW;   Kt = 24; M = 64;  base = 96;  }
  int local = fid - base;
  int mt = local / Kt, kt = local % Kt;
  int m  = mt * 16 + m4;
  int k0 = kt * 32 + (lane >> 4) * 8;
  f16x8 out;
  #pragma unroll
  for (int j = 0; j < 8; j++) out[j] = (__fp16)src[(size_t)(k0 + j) * M + m];
  *(f16x8*)(wdst + (size_t)(fid * 64 + lane) * 16) = out;
}

// ---------------------------------------------------------------------------
// Kernel 2: prologue (unchanged — verified).  256 WGs x 512 threads.
// ---------------------------------------------------------------------------
__global__ __launch_bounds__(512, 2) void prologue_kernel(
    const float* __restrict__ bert, const float* __restrict__ eps,
    const float* __restrict__ projb, const float* __restrict__ lng,
    const float* __restrict__ lnb,  const float* __restrict__ lns,
    const float* __restrict__ db1,  const float* __restrict__ db2,
    const char* __restrict__ wpack, float* __restrict__ wsz,
    float* __restrict__ dout) {
  __shared__ __attribute__((aligned(16))) char sZ[16 * 128];
  __shared__ __attribute__((aligned(16))) char sH[16 * 256];
  __shared__ f32x4  sScr[4 * 64];
  __shared__ float2 sMV[64];
  __shared__ float  sLsum[4];

  const int tid  = threadIdx.x;
  const int wave = tid >> 6, lane = tid & 63;
  const int q = lane >> 4, b = lane & 15;
  const int bg = blockIdx.x * 16 + b;
  const int b7 = b & 7;
  const f16x8* wp = (const f16x8*)wpack;
  const int u0 = wave * 16 + q * 4;

  const int zr0 = b * 128 + ((q    ) ^ b7) * 16;
  const int zr1 = b * 128 + ((q + 4) ^ b7) * 16;
  int hr[4];
  #pragma unroll
  for (int s = 0; s < 4; s++) hr[s] = b * 256 + ((4 * s + q) ^ b7) * 16;
  const int hw = b * 256 + (((2 * wave + (q >> 1)) ^ b7) * 16) + (q & 1) * 8;
  const int zw = b * 128 + (((2 * (wave & 3) + (q >> 1)) ^ b7) * 16) + (q & 1) * 8;

  const int mt = wave & 3, kh = wave >> 2;
  f32x4 hA = {0,0,0,0}, hB = {0,0,0,0};
  #pragma unroll 4
  for (int i = 0; i < 12; i++) {
    int kt = kh * 12 + i;
    f16x8 af = wp[(size_t)(96 + mt * 24 + kt) * 64 + lane];
    const float* bp = bert + (size_t)bg * 768 + kt * 32 + q * 8;
    f32x4 f0 = *(const f32x4*)bp;
    f32x4 f1 = *(const f32x4*)(bp + 4);
    f16x8 bf = pack8(f0, f1);
    if (i & 1) hB = MFMA(af, bf, hB); else hA = MFMA(af, bf, hA);
  }
  f32x4 hacc = hA + hB;
  if (wave >= 4) sScr[(wave - 4) * 64 + lane] = hacc;
  __syncthreads();

  f32x4 h = {0,0,0,0}, zc = {0,0,0,0};
  if (wave < 4) {
    h = hacc + sScr[wave * 64 + lane];
    h.x += projb[u0 + 0]; h.y += projb[u0 + 1];
    h.z += projb[u0 + 2]; h.w += projb[u0 + 3];
    float s1 = h.x + h.y + h.z + h.w;
    float s2 = h.x*h.x + h.y*h.y + h.z*h.z + h.w*h.w;
    s1 += __shfl_xor(s1, 16); s1 += __shfl_xor(s1, 32);
    s2 += __shfl_xor(s2, 16); s2 += __shfl_xor(s2, 32);
    if (q == 0) sMV[wave * 16 + b] = make_float2(s1, s2);
  }
  __syncthreads();
  if (wave < 4) {
    float t1 = 0.f, t2 = 0.f;
    #pragma unroll
    for (int w2 = 0; w2 < 4; w2++) { float2 m = sMV[w2 * 16 + b]; t1 += m.x; t2 += m.y; }
    float mu  = t1 * (1.0f / 64.0f);
    float var = t2 * (1.0f / 64.0f) - mu * mu;
    float rs  = rsqrtf(var + 1e-5f);
    float sigma = logf(1.0f + expf(lns[0]));
    f32x4 e = *(const f32x4*)(eps + (size_t)bg * 64 + u0);
    zc.x = __builtin_fmaf((h.x - mu) * rs, lng[u0+0], lnb[u0+0]);
    zc.y = __builtin_fmaf((h.y - mu) * rs, lng[u0+1], lnb[u0+1]);
    zc.z = __builtin_fmaf((h.z - mu) * rs, lng[u0+2], lnb[u0+2]);
    zc.w = __builtin_fmaf((h.w - mu) * rs, lng[u0+3], lnb[u0+3]);
    f32x4 zn = zc + sigma * e;
    *(uint2*)(sZ + zw) = make_uint2(pk2(zn.x, zn.y), pk2(zn.z, zn.w));
  }
  __syncthreads();
  {
    f16x8 w0 = wp[(size_t)(64 + wave * 2 + 0) * 64 + lane];
    f16x8 w1 = wp[(size_t)(64 + wave * 2 + 1) * 64 + lane];
    f16x8 bz0 = *(const f16x8*)(sZ + zr0);
    f16x8 bz1 = *(const f16x8*)(sZ + zr1);
    f32x4 bias = { db1[u0+0], db1[u0+1], db1[u0+2], db1[u0+3] };
    f32x4 acc = MFMA(w0, bz0, bias);
    acc = MFMA(w1, bz1, acc);
    *(uint2*)(sH + hw) = make_uint2(pk2(fast_silu(acc.x), fast_silu(acc.y)),
                                    pk2(fast_silu(acc.z), fast_silu(acc.w)));
  }
  __syncthreads();
  if (wave < 4) {
    f16x8 w0 = wp[(size_t)(80 + wave * 4 + 0) * 64 + lane];
    f16x8 w1 = wp[(size_t)(80 + wave * 4 + 1) * 64 + lane];
    f16x8 w2 = wp[(size_t)(80 + wave * 4 + 2) * 64 + lane];
    f16x8 w3 = wp[(size_t)(80 + wave * 4 + 3) * 64 + lane];
    f16x8 g0 = *(const f16x8*)(sH + hr[0]);
    f16x8 g1 = *(const f16x8*)(sH + hr[1]);
    f16x8 g2 = *(const f16x8*)(sH + hr[2]);
    f16x8 g3 = *(const f16x8*)(sH + hr[3]);
    f32x4 bias = { db2[u0+0], db2[u0+1], db2[u0+2], db2[u0+3] };
    const f32x4 z4 = {0,0,0,0};
    f32x4 aA = MFMA(w0, g0, bias); aA = MFMA(w1, g1, aA);
    f32x4 aB = MFMA(w2, g2, z4);   aB = MFMA(w3, g3, aB);
    f32x4 za = aA + aB;
    *(f32x4*)(wsz + (size_t)bg * 64 + u0) = za;
    f32x4 d = za - zc;
    float sl = d.x*d.x + d.y*d.y + d.z*d.z + d.w*d.w;
    const int offs[6] = {1, 2, 4, 8, 16, 32};
    #pragma unroll
    for (int i = 0; i < 6; i++) sl += __shfl_xor(sl, offs[i]);
    if (lane == 0) sLsum[wave] = sl;
  }
  __syncthreads();
  if (tid == 0)
    atomicAdd(dout + LOSSOFF,
              (sLsum[0] + sLsum[1] + sLsum[2] + sLsum[3]) * (1.0f / 262144.0f));
}

// ---------------------------------------------------------------------------
// Kernel 3: ODE scan — the verified R3 structure (316us ode): 256 WGs x 512
// threads (8 waves), 16 REAL rows/WG, 2 barriers/step.  R6 post-mortem
// additions (bit-identical numerics):
//  (1) SPLIT deferred decode: wave 7 ISSUES the two 2-deep decode MFMA
//      chains (eA from c8, eB from 0 — same grouping as before) at the end
//      of phase B with no dependent consumption; s_barrier does not wait on
//      MFMA register results, so wave 7 arrives at the barrier ~on time.
//      CONSUME (Gd += dt*(eA+eB), store) happens in the next B-window when
//      the results are long complete.  Removes the per-step wave-7 straggle.
//  (2) Scoped s_setprio(1) on wave 7's B-section: role asymmetry means the
//      SIMD3 arbiter should favor the wave with strictly more work.
// ---------------------------------------------------------------------------
__global__ __launch_bounds__(512, 1) void ode_kernel(
    const float* __restrict__ wsz, const char* __restrict__ wpack,
    const float* __restrict__ ob1, const float* __restrict__ cbuf,
    const float* __restrict__ ob2, const float* __restrict__ decb,
    float* __restrict__ dout) {
  __shared__ __attribute__((aligned(16))) char sH1[4096];  // h1 f16 [b][128]
  __shared__ __attribute__((aligned(16))) char sH2[4096];  // h2 f16 [b][128]

  const int tid  = threadIdx.x;
  const int wave = tid >> 6, lane = tid & 63;
  const int q = lane >> 4, b = lane & 15;
  const f16x8* wp = (const f16x8*)wpack;
  const float dtc = 1.0f / 512.0f;
  const f32x4 dt4 = {dtc, dtc, dtc, dtc};
  const f32x4 zero4 = {0,0,0,0};

  // LDS addrs: row b = 16 chunks of 16B, chunk c at (c^b): banks provably even.
  int rd[4];
  #pragma unroll
  for (int kt = 0; kt < 4; kt++) rd[kt] = b * 256 + (((kt * 4 + q) ^ b) * 16);
  const int wr = b * 256 + (((wave * 2 + (q >> 1)) ^ b) * 16) + (q & 1) * 8;

  // Persistent weight fragments
  f16x8 w2f[4], uf[4], uf8[4];
  #pragma unroll
  for (int kt = 0; kt < 4; kt++) {
    w2f[kt] = wp[(size_t)(16  + wave * 4 + kt) * 64 + lane];
    uf [kt] = wp[(size_t)(192 + wave * 4 + kt) * 64 + lane];
  }
  const bool dec = (wave == 7);
  if (dec) {
    #pragma unroll
    for (int kt = 0; kt < 4; kt++)
      uf8[kt] = wp[(size_t)(192 + 32 + kt) * 64 + lane];          // U_ext tile 8
  }
  const f32x4 b2f = *(const f32x4*)(ob2  + wave * 16 + q * 4);
  const f32x4 cw  = *(const f32x4*)(cbuf + wave * 16 + q * 4);
  const f32x4 c8  = *(const f32x4*)(cbuf + 128 + q * 4);          // tile 8 const

  // ---- init: G = z@W1 + b1 ; Gd = z@decW + decb ; h1_0 -> sH1 ; store p0 ----
  const int bg = blockIdx.x * 16 + b;
  const float* zrow = wsz + (size_t)bg * 64;
  f32x4 z0a = *(const f32x4*)(zrow + q * 8);
  f32x4 z0b = *(const f32x4*)(zrow + q * 8 + 4);
  f32x4 z1a = *(const f32x4*)(zrow + 32 + q * 8);
  f32x4 z1b = *(const f32x4*)(zrow + 32 + q * 8 + 4);
  f16x8 zf0 = pack8(z0a, z0b);
  f16x8 zf1 = pack8(z1a, z1b);

  f32x4 b1v = *(const f32x4*)(ob1 + wave * 16 + q * 4);
  f32x4 G = MFMA(wp[(size_t)(wave * 2 + 0) * 64 + lane], zf0, b1v);
  G = MFMA(wp[(size_t)(wave * 2 + 1) * 64 + lane], zf1, G);
  {
    f32x4 th = tanh4(G);
    *(uint2*)(sH1 + wr) = make_uint2(pk2(th.x, th.y), pk2(th.z, th.w));
  }

  f32x4 Gd = zero4;
  f32x4 eA = zero4, eB = zero4;   // pending (issued, unconsumed) decode partials
  float* const outp_p = dout + (size_t)bg * OT;
  float* const outp_s = dout + (size_t)TOTE + (size_t)bg * OT;
  if (dec) {
    f32x4 b1d = zero4;
    if (q == 0) { b1d.x = decb[0]; b1d.y = decb[1]; }
    Gd = MFMA(wp[(size_t)48 * 64 + lane], zf0, b1d);
    Gd = MFMA(wp[(size_t)49 * 64 + lane], zf1, Gd);
    if (q == 0) { outp_p[0] = Gd.x; outp_s[0] = Gd.y; }
  }
  wg_barrier();

  // ---- phase A: h2 = tanh(h1@W2 + b2) -> sH2 ----
  #define PHASE_A() do {                                                     \
    f16x8 p0 = *(const f16x8*)(sH1 + rd[0]);                                 \
    f16x8 p1 = *(const f16x8*)(sH1 + rd[1]);                                 \
    f16x8 p2 = *(const f16x8*)(sH1 + rd[2]);                                 \
    f16x8 p3 = *(const f16x8*)(sH1 + rd[3]);                                 \
    f32x4 a  = MFMA(w2f[0], p0, b2f);                                        \
    a  = MFMA(w2f[1], p1, a);                                                \
    f32x4 a2 = MFMA(w2f[2], p2, zero4);                                      \
    a2 = MFMA(w2f[3], p3, a2);                                               \
    f32x4 th = tanh4(a + a2);                                                \
    *(uint2*)(sH2 + wr) = make_uint2(pk2(th.x, th.y), pk2(th.z, th.w));      \
  } while (0)

  // ---- phase B G-update from read-set (Ra..Rd), write h1' ----
  #define PHASE_B_UPD(Ra,Rb,Rc,Rd_) do {                                     \
    f32x4 d  = MFMA(uf[0], Ra, cw);                                          \
    d  = MFMA(uf[1], Rb, d);                                                 \
    f32x4 d2 = MFMA(uf[2], Rc, zero4);                                       \
    d2 = MFMA(uf[3], Rd_, d2);                                               \
    G = __builtin_elementwise_fma(dt4, d + d2, G);                           \
    f32x4 th = tanh4(G);                                                     \
    *(uint2*)(sH1 + wr) = make_uint2(pk2(th.x, th.y), pk2(th.z, th.w));      \
  } while (0)

  // ---- decode ISSUE: start the two 2-deep MFMA chains, no consumption ----
  #define DEC_ISSUE(Ra,Rb,Rc,Rd_) do {                                      \
    eA = MFMA(uf8[0], Ra, c8);                                               \
    eA = MFMA(uf8[1], Rb, eA);                                               \
    eB = MFMA(uf8[2], Rc, zero4);                                            \
    eB = MFMA(uf8[3], Rd_, eB);                                              \
  } while (0)

  // ---- decode CONSUME: results long complete; same fma as before ----
  #define DEC_CONSUME(ti) do {                                              \
    Gd.x = __builtin_fmaf(dtc, eA.x + eB.x, Gd.x);                           \
    Gd.y = __builtin_fmaf(dtc, eA.y + eB.y, Gd.y);                           \
    if (q == 0) { outp_p[ti] = Gd.x; outp_s[ti] = Gd.y; }                    \
  } while (0)

  f16x8 X0, X1, X2, X3, Y0, Y1, Y2, Y3;
  #pragma unroll 1
  for (int t = 0; t < NT; t += 2) {
    // ======== step t (even): reads -> X; consume pending (Y-issued) decode
    PHASE_A();
    wg_barrier();
    X0 = *(const f16x8*)(sH2 + rd[0]);
    X1 = *(const f16x8*)(sH2 + rd[1]);
    X2 = *(const f16x8*)(sH2 + rd[2]);
    X3 = *(const f16x8*)(sH2 + rd[3]);
    if (dec) {
      __builtin_amdgcn_s_setprio(1);
      if (t > 0) DEC_CONSUME(t);
    }
    PHASE_B_UPD(X0, X1, X2, X3);
    if (dec) {
      DEC_ISSUE(X0, X1, X2, X3);
      __builtin_amdgcn_s_setprio(0);
    }
    wg_barrier();

    // ======== step t+1 (odd): reads -> Y; consume X-issued decode
    PHASE_A();
    wg_barrier();
    Y0 = *(const f16x8*)(sH2 + rd[0]);
    Y1 = *(const f16x8*)(sH2 + rd[1]);
    Y2 = *(const f16x8*)(sH2 + rd[2]);
    Y3 = *(const f16x8*)(sH2 + rd[3]);
    if (dec) {
      __builtin_amdgcn_s_setprio(1);
      DEC_CONSUME(t + 1);
    }
    PHASE_B_UPD(Y0, Y1, Y2, Y3);
    if (dec) {
      DEC_ISSUE(Y0, Y1, Y2, Y3);
      __builtin_amdgcn_s_setprio(0);
    }
    wg_barrier();
  }
  // epilogue: consume the last (Y-issued) decode -> outp[NT]
  if (dec) DEC_CONSUME(NT);
  #undef PHASE_A
  #undef PHASE_B_UPD
  #undef DEC_ISSUE
  #undef DEC_CONSUME
}

// ---------------------------------------------------------------------------
extern "C" void kernel_launch(void* const* d_in, const int* in_sizes, int n_in,
                              void* d_out, int out_size, void* d_ws, size_t ws_size,
                              hipStream_t stream) {
  const float* bert  = (const float*)d_in[0];
  const float* eps   = (const float*)d_in[3];
  const float* projW = (const float*)d_in[4];
  const float* projb = (const float*)d_in[5];
  const float* lng   = (const float*)d_in[6];
  const float* lnb   = (const float*)d_in[7];
  const float* lns   = (const float*)d_in[8];
  const float* denW1 = (const float*)d_in[9];
  const float* denb1 = (const float*)d_in[10];
  const float* denW2 = (const float*)d_in[11];
  const float* denb2 = (const float*)d_in[12];
  const float* odeW1 = (const float*)d_in[13];
  const float* odeb1 = (const float*)d_in[14];
  const float* odeW2 = (const float*)d_in[15];
  const float* odeb2 = (const float*)d_in[16];
  const float* odeW3 = (const float*)d_in[17];
  // d_in[18] = odeb3 (folded into cbuf), d_in[19] = decW, d_in[20] = decb
  const float* odeb3 = (const float*)d_in[18];
  const float* decW  = (const float*)d_in[19];
  const float* decb  = (const float*)d_in[20];
  float* dout = (float*)d_out;

  float* wsz  = (float*)d_ws;
  char*  wpak = (char*)d_ws + WS_WPAK;
  float* cbuf = (float*)((char*)d_ws + WS_CBUF);

  pack_kernel<<<58, 256, 0, stream>>>(odeW1, odeW2, decW, denW1, denW2, projW,
                                      odeW3, odeb3, cbuf, wpak, dout);
  prologue_kernel<<<256, 512, 0, stream>>>(bert, eps, projb, lng, lnb, lns,
                                           denb1, denb2, wpak, wsz, dout);
  ode_kernel<<<256, 512, 0, stream>>>(wsz, wpak, odeb1, cbuf, odeb2, decb, dout);
}